// Round 10
// baseline (4958.284 us; speedup 1.0000x reference)
//
#include <hip/hip_runtime.h>
#include <hip/hip_bf16.h>
#include <math.h>

typedef _Float16 f16;
typedef __attribute__((ext_vector_type(8))) _Float16 f16x8;
typedef __attribute__((ext_vector_type(4))) _Float16 f16x4;
typedef __attribute__((ext_vector_type(4))) float f32x4;

#define DINLINE __device__ __forceinline__

DINLINE float gelu_fast(float x) {
  // gelu ~= x * sigmoid(2t), t = 0.79788456*x*(1+0.044715x^2)
  float x2 = x * x;
  float z = x * __builtin_fmaf(-0.10294537f, x2, -2.30211422f);
  float E = __builtin_amdgcn_exp2f(z);
  return x * __builtin_amdgcn_rcpf(1.0f + E);
}
DINLINE void gload16(const void* g, void* l) {
  __builtin_amdgcn_global_load_lds((const __attribute__((address_space(1))) void*)g,
                                   (__attribute__((address_space(3))) void*)l, 16, 0, 0);
}

#define BAR       __builtin_amdgcn_s_barrier()
#define WAITLGKM  asm volatile("s_waitcnt lgkmcnt(0)" ::: "memory")
#define WAITVM(n) asm volatile("s_waitcnt vmcnt(" #n ")" ::: "memory")

// ---------------------------------------------------------------------------
// GEMM 128x128 tile, BK=32, 4 waves (2x2, wave-tile 64x64), 256 thr, 32KB
// double-buffered LDS -> 4 blocks/CU: independent blocks fill each other's
// barrier/vmcnt stalls (m114 mechanism). STAGE = 4 gloads/thread (1024 16B
// chunks total = 2 matrices x 128 rows x 4 slots); counted vmcnt(4) keeps
// tile t+1's loads in flight, never drained mid-loop. Conflict-free XOR
// slot layout. Operand-swapped MFMA -> 4 consecutive C-cols/thread.
// C = A[M,K] @ Bt[N,K]^T. EPI: 1=gelu, 2=add f16 Cin, 4=store f16, 8=scale.
// Requires M%128==0, N%128==0, K%32==0, K>=64.
// ---------------------------------------------------------------------------
template <int EPI>
__global__ __launch_bounds__(256, 4) void gemm128(
    const f16* __restrict__ A, const f16* __restrict__ Bt,
    const float* __restrict__ bias, const f16* __restrict__ Cin,
    float* __restrict__ Cf, f16* __restrict__ Cb,
    const float* __restrict__ scale_ptr,
    int N, int K, int nct)
{
  __shared__ alignas(16) f16 sm[2][2][4096];   // [buf][A/B][128 rows x 32]

  // bijective XCD-chunked swizzle
  const int nwg = (int)gridDim.x;
  const int gid = (int)blockIdx.x;
  const int q = nwg >> 3, r = nwg & 7;
  const int xcd = gid & 7, idx = gid >> 3;
  const int swz = (xcd < r ? xcd * (q + 1) : r * (q + 1) + (xcd - r) * q) + idx;
  const int rt = swz / nct, ct = swz - rt * nct;
  const int m0 = rt << 7, n0 = ct << 7;

  const int tid = (int)threadIdx.x;
  const int lane = tid & 63;
  const int wid = tid >> 6;
  const int wr = wid >> 1, wcn = wid & 1;      // wave -> 64x64 output quadrant

  const int rsel = lane & 15, khi = lane >> 4;
  const int sx = (khi ^ ((rsel >> 1) & 3)) << 3;

  f32x4 acc[4][4] = {};
  f16x8 aF[4], bF[4];

  const int NT = K >> 5;

// stage 128x32 A + 128x32 B (16KB) = 4 gloads/thread, 1024 chunks total.
// slot s (0..1023): mat = s>>9, within-mat sm = s&511, row = sm>>2,
// phys slot = sm&3, logical slot = phys ^ ((row>>1)&3)  (inverse swizzle)
#define STAGE(b, k0)                                                          \
  {                                                                           \
    _Pragma("unroll")                                                         \
    for (int _g = 0; _g < 4; ++_g) {                                          \
      const int _s = _g * 256 + tid;                                          \
      const int _mat = _s >> 9, _sm = _s & 511;                               \
      const int _row = _sm >> 2;                                              \
      const int _ls = (_sm & 3) ^ ((_row >> 1) & 3);                          \
      const f16* _src = _mat ? Bt + (size_t)(n0 + _row) * K                   \
                             : A + (size_t)(m0 + _row) * K;                   \
      gload16(_src + (k0) + (_ls << 3), &sm[b][_mat][_sm * 8]);               \
    }                                                                         \
  }

#define DSRA(b)                                                               \
  {                                                                           \
    _Pragma("unroll")                                                         \
    for (int _i = 0; _i < 4; ++_i)                                            \
      aF[_i] = *(const f16x8*)(&sm[b][0][(wr * 64 + _i * 16 + rsel) * 32 + sx]); \
  }

#define DSRB(b)                                                               \
  {                                                                           \
    _Pragma("unroll")                                                         \
    for (int _i = 0; _i < 4; ++_i)                                            \
      bF[_i] = *(const f16x8*)(&sm[b][1][(wcn * 64 + _i * 16 + rsel) * 32 + sx]); \
  }

// operand-swapped: per thread, frag holds 4 consecutive C-columns
#define MMC                                                                   \
  {                                                                           \
    __builtin_amdgcn_s_setprio(1);                                            \
    _Pragma("unroll")                                                         \
    for (int _m = 0; _m < 4; ++_m)                                            \
      _Pragma("unroll")                                                       \
      for (int _n = 0; _n < 4; ++_n)                                          \
        acc[_m][_n] = __builtin_amdgcn_mfma_f32_16x16x32_f16(                 \
            bF[_n], aF[_m], acc[_m][_n], 0, 0, 0);                            \
    __builtin_amdgcn_s_setprio(0);                                            \
  }

  STAGE(0, 0);
  for (int t = 0; t < NT; ++t) {
    const int b = t & 1;
    if (t + 1 < NT) {
      if (b) STAGE(0, (t + 1) << 5) else STAGE(1, (t + 1) << 5)
      WAITVM(4);          // tile t fully landed; t+1's 4 stay in flight
    } else {
      WAITVM(0);
    }
    BAR;
    DSRA(b); DSRB(b); WAITLGKM; MMC;
    BAR;                  // all waves done reading buf b
  }

  // ---- vector epilogue: 4 consecutive cols per (m,n) frag ----
  const float scale = (EPI & 8) ? scale_ptr[0] : 1.0f;
  const int R0 = m0 + wr * 64, C0 = n0 + wcn * 64;
#pragma unroll
  for (int m = 0; m < 4; ++m) {
    const int row = R0 + m * 16 + rsel;
#pragma unroll
    for (int n = 0; n < 4; ++n) {
      const int col = C0 + n * 16 + (khi << 2);
      f32x4 v = acc[m][n];
      if (EPI & 8) {
#pragma unroll
        for (int j = 0; j < 4; ++j) v[j] *= scale;
      }
      f32x4 bb = *(const f32x4*)(bias + col);
#pragma unroll
      for (int j = 0; j < 4; ++j) v[j] += bb[j];
      if (EPI & 1) {
#pragma unroll
        for (int j = 0; j < 4; ++j) v[j] = gelu_fast(v[j]);
      }
      if (EPI & 2) {
        f16x4 c4 = *(const f16x4*)(Cin + (size_t)row * N + col);
#pragma unroll
        for (int j = 0; j < 4; ++j) v[j] += (float)c4[j];
      }
      if (EPI & 4) {
        f16x4 o;
#pragma unroll
        for (int j = 0; j < 4; ++j) o[j] = (f16)v[j];
        *(f16x4*)(Cb + (size_t)row * N + col) = o;
      } else {
        *(f32x4*)(Cf + (size_t)row * N + col) = v;
      }
    }
  }
#undef STAGE
#undef DSRA
#undef DSRB
#undef MMC
}

// ---------------------------------------------------------------------------
__global__ __launch_bounds__(256) void ln_f16(
    const f16* __restrict__ X, const float* __restrict__ g,
    const float* __restrict__ b, f16* __restrict__ Y, int ntok)
{
  const int lane = threadIdx.x & 63;
  const int c = lane * 8;
  const f32x4 g0 = *(const f32x4*)(g + c), g1 = *(const f32x4*)(g + c + 4);
  const f32x4 b0 = *(const f32x4*)(b + c), b1 = *(const f32x4*)(b + c + 4);
  for (int token = blockIdx.x * 4 + (threadIdx.x >> 6); token < ntok;
       token += gridDim.x * 4) {
    f16x8 v = *(const f16x8*)(X + (size_t)token * 512 + c);
    float vf[8];
    float s = 0.f, s2 = 0.f;
#pragma unroll
    for (int j = 0; j < 8; ++j) { vf[j] = (float)v[j]; s += vf[j]; s2 += vf[j] * vf[j]; }
#pragma unroll
    for (int o = 32; o > 0; o >>= 1) { s += __shfl_xor(s, o, 64); s2 += __shfl_xor(s2, o, 64); }
    const float mean = s * (1.f / 512.f);
    const float inv = rsqrtf(s2 * (1.f / 512.f) - mean * mean + 1e-5f);
    f16x8 o8;
#pragma unroll
    for (int j = 0; j < 4; ++j) {
      o8[j]     = (f16)((vf[j] - mean) * inv * g0[j] + b0[j]);
      o8[4 + j] = (f16)((vf[4 + j] - mean) * inv * g1[j] + b1[j]);
    }
    *(f16x8*)(Y + (size_t)token * 512 + c) = o8;
  }
}

__global__ __launch_bounds__(256) void cvt_f32_f16(const float* __restrict__ X,
                                                   f16* __restrict__ Y, long n8)
{
  const long i = (long)blockIdx.x * 256 + threadIdx.x;
  if (i >= n8) return;
  f32x4 v0 = *(const f32x4*)(X + i * 8), v1 = *(const f32x4*)(X + i * 8 + 4);
  f16x8 o8;
#pragma unroll
  for (int j = 0; j < 4; ++j) { o8[j] = (f16)v0[j]; o8[4 + j] = (f16)v1[j]; }
  *(f16x8*)(Y + i * 8) = o8;
}

__global__ __launch_bounds__(256) void w_tr_tiled(const float* __restrict__ W,
                                                  f16* __restrict__ Wt, int K, int N)
{
  __shared__ f16 td[64][66];
  const int nkt = K >> 6;
  const int kt = blockIdx.x % nkt, nt = blockIdx.x / nkt;
  const int k0 = kt << 6, n0 = nt << 6;
  const int col = threadIdx.x & 63, rq = threadIdx.x >> 6;
#pragma unroll
  for (int j = 0; j < 16; ++j) {
    const int row = j * 4 + rq;
    td[row][col] = (f16)W[(size_t)(k0 + row) * N + n0 + col];
  }
  __syncthreads();
#pragma unroll
  for (int j = 0; j < 16; ++j) {
    const int nrow = j * 4 + rq;
    Wt[(size_t)(n0 + nrow) * K + k0 + col] = td[col][nrow];
  }
}

// ---------------------------------------------------------------------------
template <int SHIFT>
__global__ __launch_bounds__(256) void win_attn(const f16* __restrict__ QKV,
                                                f16* __restrict__ O)
{
  __shared__ alignas(16) f16 kv[2][16][1160];
  const int wl0 = (int)blockIdx.x * 2;
  const int tid = (int)threadIdx.x;

  for (int i = tid; i < 4096; i += 256) {
    const int win = i >> 11;
    const int rem = i & 2047;
    const int row = rem >> 7;
    const int c8 = rem & 127;
    const int src = ((wl0 + win) * 16 + row + SHIFT) % 49152;
    const int sect = c8 >> 6;
    const int hh = (c8 >> 3) & 7;
    const int dd = (c8 & 7) * 8;
    *(f16x8*)(&kv[win][row][sect * 576 + hh * 72 + dd]) =
        *(const f16x8*)(QKV + (size_t)src * 1536 + 512 + c8 * 8);
  }

  const int win = tid >> 7, h = (tid >> 4) & 7, qi = tid & 15;
  const int qtok = ((wl0 + win) * 16 + qi + SHIFT) % 49152;
  f16x8 qv[8];
#pragma unroll
  for (int c8 = 0; c8 < 8; ++c8)
    qv[c8] = *(const f16x8*)(QKV + (size_t)qtok * 1536 + h * 64 + c8 * 8);

  __syncthreads();

  float sc[16];
  float mx = -1e30f;
#pragma unroll
  for (int kj = 0; kj < 16; ++kj) {
    const f16* kr = &kv[win][kj][h * 72];
    float s = 0.f;
#pragma unroll
    for (int c8 = 0; c8 < 8; ++c8) {
      f16x8 k8 = *(const f16x8*)(kr + c8 * 8);
#pragma unroll
      for (int j = 0; j < 8; ++j) s += (float)qv[c8][j] * (float)k8[j];
    }
    s *= 0.125f;
    sc[kj] = s;
    mx = fmaxf(mx, s);
  }
  float sum = 0.f;
#pragma unroll
  for (int kj = 0; kj < 16; ++kj) { sc[kj] = expf(sc[kj] - mx); sum += sc[kj]; }
  const float inv = 1.f / sum;
  float ov[64] = {};
#pragma unroll
  for (int kj = 0; kj < 16; ++kj) {
    const float a = sc[kj] * inv;
    const f16* vr = &kv[win][kj][576 + h * 72];
#pragma unroll
    for (int c8 = 0; c8 < 8; ++c8) {
      f16x8 v8 = *(const f16x8*)(vr + c8 * 8);
#pragma unroll
      for (int j = 0; j < 8; ++j) ov[c8 * 8 + j] += a * (float)v8[j];
    }
  }
  f16* orow = O + (size_t)qtok * 512 + h * 64;
#pragma unroll
  for (int c8 = 0; c8 < 8; ++c8) {
    f16x8 t;
#pragma unroll
    for (int j = 0; j < 8; ++j) t[j] = (f16)ov[c8 * 8 + j];
    *(f16x8*)(orow + c8 * 8) = t;
  }
}

// ---------------------------------------------------------------------------
__global__ __launch_bounds__(256) void sn_sigma(const float* __restrict__ W,
                                                const float* __restrict__ u,
                                                float* __restrict__ inv_sigma)
{
  __shared__ float vsh[512];
  __shared__ float ush[256];
  __shared__ float red[256];
  const int t = (int)threadIdx.x;
  ush[t] = u[t];
  __syncthreads();
  float a0 = 0.f, a1 = 0.f;
  for (int j = 0; j < 256; ++j) {
    a0 += W[t * 256 + j] * ush[j];
    a1 += W[(t + 256) * 256 + j] * ush[j];
  }
  vsh[t] = a0; vsh[t + 256] = a1;
  red[t] = a0 * a0 + a1 * a1;
  __syncthreads();
  for (int s = 128; s > 0; s >>= 1) { if (t < s) red[t] += red[t + s]; __syncthreads(); }
  const float nv = sqrtf(red[0]) + 1e-12f;
  __syncthreads();
  const float invv = 1.f / nv;
  vsh[t] *= invv; vsh[t + 256] *= invv;
  __syncthreads();
  float u2 = 0.f;
  for (int i = 0; i < 512; ++i) u2 += vsh[i] * W[i * 256 + t];
  red[t] = u2 * u2;
  __syncthreads();
  for (int s = 128; s > 0; s >>= 1) { if (t < s) red[t] += red[t + s]; __syncthreads(); }
  const float nu = sqrtf(red[0]) + 1e-12f;
  __syncthreads();
  ush[t] = u2 / nu;
  __syncthreads();
  float d0 = 0.f, d1 = 0.f;
  for (int j = 0; j < 256; ++j) {
    d0 += W[t * 256 + j] * ush[j];
    d1 += W[(t + 256) * 256 + j] * ush[j];
  }
  red[t] = vsh[t] * d0 + vsh[t + 256] * d1;
  __syncthreads();
  for (int s = 128; s > 0; s >>= 1) { if (t < s) red[t] += red[t + s]; __syncthreads(); }
  if (t == 0) inv_sigma[0] = 1.f / red[0];
}

__global__ void fill_sentinel(float* __restrict__ out, long n, float val)
{
  const long i = (long)blockIdx.x * 256 + threadIdx.x;
  for (long k = i; k < n; k += (long)gridDim.x * 256) out[k] = val;
}

// ---------------------------------------------------------------------------
extern "C" void kernel_launch(void* const* d_in, const int* in_sizes, int n_in,
                              void* d_out, int out_size, void* d_ws, size_t ws_size,
                              hipStream_t stream)
{
  const int M = 196608;
  const int MC = 49152;
  constexpr size_t OFF_U   = 201326592ull;
  constexpr size_t OFF_OH  = 201326592ull + 150994944ull;
  constexpr size_t OFF_WT  = 402653184ull;
  constexpr size_t OFF_SIG = 415760384ull;
  constexpr size_t NEED    = OFF_SIG + 256ull;

  if (ws_size < NEED) {
    fill_sentinel<<<2048, 256, 0, stream>>>((float*)d_out, (long)out_size,
                                            (float)(ws_size >> 20));
    return;
  }

  char* ws = (char*)d_ws;
  f16* R     = (f16*)(ws);
  f16* U     = (f16*)(ws + OFF_U);
  f16* OH    = (f16*)(ws + OFF_OH);
  f16* WT    = (f16*)(ws + OFF_WT);
  float* sig = (float*)(ws + OFF_SIG);
  f16* X     = (f16*)d_out;

  const float* ff1_b = (const float*)d_in[2];
  const float* ff2_b = (const float*)d_in[28];

  f16* W_FF1 = WT;
  auto W_QKV = [&](int blk) { return WT + (blk ? 3276800 : 131072); };
  auto W_PW  = [&](int blk) { return WT + (blk ? 4063232 : 917504); };
  auto W_M1  = [&](int blk) { return WT + (blk ? 4325376 : 1179648); };
  auto W_M2  = [&](int blk) { return WT + (blk ? 5373952 : 2228224); };
  f16* W_FF2 = WT + 6422528;

  w_tr_tiled<<<32, 256, 0, stream>>>((const float*)d_in[1], W_FF1, 256, 512);
  for (int blk = 0; blk < 2; ++blk) {
    w_tr_tiled<<<192, 256, 0, stream>>>((const float*)d_in[blk ? 17 : 5], W_QKV(blk), 512, 1536);
    w_tr_tiled<<<64, 256, 0, stream>>>((const float*)d_in[blk ? 19 : 7], W_PW(blk), 512, 512);
    w_tr_tiled<<<256, 256, 0, stream>>>((const float*)d_in[blk ? 23 : 11], W_M1(blk), 512, 2048);
    w_tr_tiled<<<256, 256, 0, stream>>>((const float*)d_in[blk ? 25 : 13], W_M2(blk), 2048, 512);
  }
  w_tr_tiled<<<32, 256, 0, stream>>>((const float*)d_in[27], W_FF2, 512, 256);
  sn_sigma<<<1, 256, 0, stream>>>((const float*)d_in[27], (const float*)d_in[29], sig);

  // ---- ff1: R = gelu(x @ ff1_w + b) ----
  cvt_f32_f16<<<24576, 256, 0, stream>>>((const float*)d_in[0], U, (long)M * 256 / 8);
  gemm128<5><<<6144, 256, 0, stream>>>(U, W_FF1, ff1_b, nullptr, nullptr, R, nullptr,
                                       512, 256, 4);

  for (int blk = 0; blk < 2; ++blk) {
    const float* ln1g = (const float*)d_in[blk ? 15 : 3];
    const float* ln1b = (const float*)d_in[blk ? 16 : 4];
    const float* qkvb = (const float*)d_in[blk ? 18 : 6];
    const float* pb   = (const float*)d_in[blk ? 20 : 8];
    const float* ln2g = (const float*)d_in[blk ? 21 : 9];
    const float* ln2b = (const float*)d_in[blk ? 22 : 10];
    const float* m1b  = (const float*)d_in[blk ? 24 : 12];
    const float* m2b  = (const float*)d_in[blk ? 26 : 14];

    // attention: x += proj(attn(ln1(x)))
    ln_f16<<<4096, 256, 0, stream>>>(R, ln1g, ln1b, X, M);
    for (int mc = 0; mc < 4; ++mc) {
      const size_t ro = (size_t)mc * MC * 512;
      gemm128<4><<<4608, 256, 0, stream>>>(X + ro, W_QKV(blk), qkvb, nullptr,
                                           nullptr, U, nullptr, 1536, 512, 12);
      if (blk == 0) win_attn<0><<<1536, 256, 0, stream>>>(U, OH);
      else          win_attn<8><<<1536, 256, 0, stream>>>(U, OH);
      gemm128<6><<<1536, 256, 0, stream>>>(OH, W_PW(blk), pb, R + ro,
                                           nullptr, R + ro, nullptr, 512, 512, 4);
    }
    // MLP: x += gelu(ln2(x) @ m1) @ m2
    ln_f16<<<4096, 256, 0, stream>>>(R, ln2g, ln2b, X, M);
    for (int mc = 0; mc < 4; ++mc) {
      const size_t ro = (size_t)mc * MC * 512;
      gemm128<5><<<6144, 256, 0, stream>>>(X + ro, W_M1(blk), m1b, nullptr,
                                           nullptr, U, nullptr, 2048, 512, 16);
      gemm128<6><<<1536, 256, 0, stream>>>(U, W_M2(blk), m2b, R + ro,
                                           nullptr, R + ro, nullptr, 512, 2048, 4);
    }
  }

  // ---- spectral-norm linear -> d_out (fp32) ----
  gemm128<8><<<3072, 256, 0, stream>>>(R, W_FF2, ff2_b, nullptr, (float*)d_out,
                                       nullptr, sig, 256, 512, 2);
}

// Round 11
// 4856.579 us; speedup vs baseline: 1.0209x; 1.0209x over previous
//
#include <hip/hip_runtime.h>
#include <hip/hip_bf16.h>
#include <math.h>

typedef _Float16 f16;
typedef __attribute__((ext_vector_type(8))) _Float16 f16x8;
typedef __attribute__((ext_vector_type(4))) _Float16 f16x4;
typedef __attribute__((ext_vector_type(4))) float f32x4;

#define DINLINE __device__ __forceinline__

DINLINE float gelu_fast(float x) {
  // gelu ~= x * sigmoid(2t), t = 0.79788456*x*(1+0.044715x^2)
  float x2 = x * x;
  float z = x * __builtin_fmaf(-0.10294537f, x2, -2.30211422f);
  float E = __builtin_amdgcn_exp2f(z);
  return x * __builtin_amdgcn_rcpf(1.0f + E);
}
DINLINE void gload16(const void* g, void* l) {
  __builtin_amdgcn_global_load_lds((const __attribute__((address_space(1))) void*)g,
                                   (__attribute__((address_space(3))) void*)l, 16, 0, 0);
}

#define BAR       __builtin_amdgcn_s_barrier()
#define WAITLGKM  asm volatile("s_waitcnt lgkmcnt(0)" ::: "memory")
#define WAITVM(n) asm volatile("s_waitcnt vmcnt(" #n ")" ::: "memory")

// ---------------------------------------------------------------------------
// GEMM 128x256 tile (BM=128, BN=256), BK=32, 512 thr / 8 waves (2M x 4N,
// wave-tile 64x64), 48KB double-buffered LDS -> 2 blocks/CU. Wide BN halves
// the A-panel L2/L3 re-read traffic (nct = N/256 column passes instead of
// N/128) — the identified bottleneck (r10 analysis: all pipes <41%, time
// tracks cache-path bytes). 2-phase counted-vmcnt loop: STAGE = 3 gloads/
// thread (A 128x32 + B 256x32 = 1536 16B chunks / 512 thr), vmcnt(3) keeps
// next tile's loads in flight, never drained mid-loop. Conflict-free XOR
// slot layout per 128x32 region (B = 2 regions). Operand-swapped MFMA ->
// 4 consecutive C-cols/thread, coalesced vector epilogue.
// C = A[M,K] @ Bt[N,K]^T. EPI: 1=gelu, 2=add f16 Cin, 4=store f16, 8=scale.
// Requires M%128==0, N%256==0, K%32==0, K>=64.
// ---------------------------------------------------------------------------
template <int EPI>
__global__ __launch_bounds__(512, 4) void gemm(
    const f16* __restrict__ A, const f16* __restrict__ Bt,
    const float* __restrict__ bias, const f16* __restrict__ Cin,
    float* __restrict__ Cf, f16* __restrict__ Cb,
    const float* __restrict__ scale_ptr,
    int N, int K, int nct)
{
  __shared__ alignas(16) f16 sm[2][3][4096];   // [buf][A|B0|B1][128 rows x 32]

  // bijective XCD-chunked swizzle
  const int nwg = (int)gridDim.x;
  const int gid = (int)blockIdx.x;
  const int q = nwg >> 3, r = nwg & 7;
  const int xcd = gid & 7, idx = gid >> 3;
  const int swz = (xcd < r ? xcd * (q + 1) : r * (q + 1) + (xcd - r) * q) + idx;
  const int rt = swz / nct, ct = swz - rt * nct;
  const int m0 = rt << 7, n0 = ct << 8;        // 128-row x 256-col tile

  const int tid = (int)threadIdx.x;
  const int lane = tid & 63;
  const int wid = tid >> 6;
  const int wr = wid >> 2, wcn = wid & 3;      // wave -> 64x64 output quadrant

  const int rsel = lane & 15, khi = lane >> 4;
  const int sx = (khi ^ ((rsel >> 1) & 3)) << 3;

  const int breg = 1 + (wcn >> 1);             // B region for this wave
  const int brow0 = (wcn & 1) * 64;            // row base within region

  f32x4 acc[4][4] = {};
  f16x8 aF[4], bF[4];

  const int NT = K >> 5;

// stage 128x32 A + 256x32 B (24KB) = 3 gloads/thread, 1536 chunks.
// slot s: region = s>>9 (0=A,1=B rows 0..127,2=B rows 128..255),
// smi = s&511, row = smi>>2, phys slot = smi&3,
// logical slot = phys ^ ((row>>1)&3)  (inverse swizzle on global source)
#define STAGE(b, k0)                                                          \
  {                                                                           \
    _Pragma("unroll")                                                         \
    for (int _g = 0; _g < 3; ++_g) {                                          \
      const int _s = _g * 512 + tid;                                          \
      const int _reg = _s >> 9, _smi = _s & 511;                              \
      const int _row = _smi >> 2;                                             \
      const int _ls = (_smi & 3) ^ ((_row >> 1) & 3);                         \
      const f16* _src = (_reg == 0)                                           \
          ? A + (size_t)(m0 + _row) * K                                       \
          : Bt + (size_t)(n0 + ((_reg - 1) << 7) + _row) * K;                 \
      gload16(_src + (k0) + (_ls << 3), &sm[b][_reg][_smi * 8]);              \
    }                                                                         \
  }

#define DSRA(b)                                                               \
  {                                                                           \
    _Pragma("unroll")                                                         \
    for (int _i = 0; _i < 4; ++_i)                                            \
      aF[_i] = *(const f16x8*)(&sm[b][0][(wr * 64 + _i * 16 + rsel) * 32 + sx]); \
  }

#define DSRB(b)                                                               \
  {                                                                           \
    _Pragma("unroll")                                                         \
    for (int _i = 0; _i < 4; ++_i)                                            \
      bF[_i] = *(const f16x8*)(&sm[b][breg][(brow0 + _i * 16 + rsel) * 32 + sx]); \
  }

// operand-swapped: per thread, frag holds 4 consecutive C-columns
#define MMC                                                                   \
  {                                                                           \
    __builtin_amdgcn_s_setprio(1);                                            \
    _Pragma("unroll")                                                         \
    for (int _m = 0; _m < 4; ++_m)                                            \
      _Pragma("unroll")                                                       \
      for (int _n = 0; _n < 4; ++_n)                                          \
        acc[_m][_n] = __builtin_amdgcn_mfma_f32_16x16x32_f16(                 \
            bF[_n], aF[_m], acc[_m][_n], 0, 0, 0);                            \
    __builtin_amdgcn_s_setprio(0);                                            \
  }

  STAGE(0, 0);
  for (int t = 0; t < NT; ++t) {
    const int b = t & 1;
    if (t + 1 < NT) {
      if (b) STAGE(0, (t + 1) << 5) else STAGE(1, (t + 1) << 5)
      WAITVM(3);          // tile t fully landed; t+1's 3 stay in flight
    } else {
      WAITVM(0);
    }
    BAR;
    DSRA(b); DSRB(b); WAITLGKM; MMC;
    BAR;                  // all waves done reading buf b
  }

  // ---- vector epilogue: 4 consecutive cols per (m,n) frag ----
  const float scale = (EPI & 8) ? scale_ptr[0] : 1.0f;
  const int R0 = m0 + wr * 64, C0 = n0 + wcn * 64;
#pragma unroll
  for (int m = 0; m < 4; ++m) {
    const int row = R0 + m * 16 + rsel;
#pragma unroll
    for (int n = 0; n < 4; ++n) {
      const int col = C0 + n * 16 + (khi << 2);
      f32x4 v = acc[m][n];
      if (EPI & 8) {
#pragma unroll
        for (int j = 0; j < 4; ++j) v[j] *= scale;
      }
      f32x4 bb = *(const f32x4*)(bias + col);
#pragma unroll
      for (int j = 0; j < 4; ++j) v[j] += bb[j];
      if (EPI & 1) {
#pragma unroll
        for (int j = 0; j < 4; ++j) v[j] = gelu_fast(v[j]);
      }
      if (EPI & 2) {
        f16x4 c4 = *(const f16x4*)(Cin + (size_t)row * N + col);
#pragma unroll
        for (int j = 0; j < 4; ++j) v[j] += (float)c4[j];
      }
      if (EPI & 4) {
        f16x4 o;
#pragma unroll
        for (int j = 0; j < 4; ++j) o[j] = (f16)v[j];
        *(f16x4*)(Cb + (size_t)row * N + col) = o;
      } else {
        *(f32x4*)(Cf + (size_t)row * N + col) = v;
      }
    }
  }
#undef STAGE
#undef DSRA
#undef DSRB
#undef MMC
}

// ---------------------------------------------------------------------------
__global__ __launch_bounds__(256) void ln_f16(
    const f16* __restrict__ X, const float* __restrict__ g,
    const float* __restrict__ b, f16* __restrict__ Y, int ntok)
{
  const int lane = threadIdx.x & 63;
  const int c = lane * 8;
  const f32x4 g0 = *(const f32x4*)(g + c), g1 = *(const f32x4*)(g + c + 4);
  const f32x4 b0 = *(const f32x4*)(b + c), b1 = *(const f32x4*)(b + c + 4);
  for (int token = blockIdx.x * 4 + (threadIdx.x >> 6); token < ntok;
       token += gridDim.x * 4) {
    f16x8 v = *(const f16x8*)(X + (size_t)token * 512 + c);
    float vf[8];
    float s = 0.f, s2 = 0.f;
#pragma unroll
    for (int j = 0; j < 8; ++j) { vf[j] = (float)v[j]; s += vf[j]; s2 += vf[j] * vf[j]; }
#pragma unroll
    for (int o = 32; o > 0; o >>= 1) { s += __shfl_xor(s, o, 64); s2 += __shfl_xor(s2, o, 64); }
    const float mean = s * (1.f / 512.f);
    const float inv = rsqrtf(s2 * (1.f / 512.f) - mean * mean + 1e-5f);
    f16x8 o8;
#pragma unroll
    for (int j = 0; j < 4; ++j) {
      o8[j]     = (f16)((vf[j] - mean) * inv * g0[j] + b0[j]);
      o8[4 + j] = (f16)((vf[4 + j] - mean) * inv * g1[j] + b1[j]);
    }
    *(f16x8*)(Y + (size_t)token * 512 + c) = o8;
  }
}

__global__ __launch_bounds__(256) void cvt_f32_f16(const float* __restrict__ X,
                                                   f16* __restrict__ Y, long n8)
{
  const long i = (long)blockIdx.x * 256 + threadIdx.x;
  if (i >= n8) return;
  f32x4 v0 = *(const f32x4*)(X + i * 8), v1 = *(const f32x4*)(X + i * 8 + 4);
  f16x8 o8;
#pragma unroll
  for (int j = 0; j < 4; ++j) { o8[j] = (f16)v0[j]; o8[4 + j] = (f16)v1[j]; }
  *(f16x8*)(Y + i * 8) = o8;
}

__global__ __launch_bounds__(256) void w_tr_tiled(const float* __restrict__ W,
                                                  f16* __restrict__ Wt, int K, int N)
{
  __shared__ f16 td[64][66];
  const int nkt = K >> 6;
  const int kt = blockIdx.x % nkt, nt = blockIdx.x / nkt;
  const int k0 = kt << 6, n0 = nt << 6;
  const int col = threadIdx.x & 63, rq = threadIdx.x >> 6;
#pragma unroll
  for (int j = 0; j < 16; ++j) {
    const int row = j * 4 + rq;
    td[row][col] = (f16)W[(size_t)(k0 + row) * N + n0 + col];
  }
  __syncthreads();
#pragma unroll
  for (int j = 0; j < 16; ++j) {
    const int nrow = j * 4 + rq;
    Wt[(size_t)(n0 + nrow) * K + k0 + col] = td[col][nrow];
  }
}

// ---------------------------------------------------------------------------
template <int SHIFT>
__global__ __launch_bounds__(256) void win_attn(const f16* __restrict__ QKV,
                                                f16* __restrict__ O)
{
  __shared__ alignas(16) f16 kv[2][16][1160];
  const int wl0 = (int)blockIdx.x * 2;
  const int tid = (int)threadIdx.x;

  for (int i = tid; i < 4096; i += 256) {
    const int win = i >> 11;
    const int rem = i & 2047;
    const int row = rem >> 7;
    const int c8 = rem & 127;
    const int src = ((wl0 + win) * 16 + row + SHIFT) % 49152;
    const int sect = c8 >> 6;
    const int hh = (c8 >> 3) & 7;
    const int dd = (c8 & 7) * 8;
    *(f16x8*)(&kv[win][row][sect * 576 + hh * 72 + dd]) =
        *(const f16x8*)(QKV + (size_t)src * 1536 + 512 + c8 * 8);
  }

  const int win = tid >> 7, h = (tid >> 4) & 7, qi = tid & 15;
  const int qtok = ((wl0 + win) * 16 + qi + SHIFT) % 49152;
  f16x8 qv[8];
#pragma unroll
  for (int c8 = 0; c8 < 8; ++c8)
    qv[c8] = *(const f16x8*)(QKV + (size_t)qtok * 1536 + h * 64 + c8 * 8);

  __syncthreads();

  float sc[16];
  float mx = -1e30f;
#pragma unroll
  for (int kj = 0; kj < 16; ++kj) {
    const f16* kr = &kv[win][kj][h * 72];
    float s = 0.f;
#pragma unroll
    for (int c8 = 0; c8 < 8; ++c8) {
      f16x8 k8 = *(const f16x8*)(kr + c8 * 8);
#pragma unroll
      for (int j = 0; j < 8; ++j) s += (float)qv[c8][j] * (float)k8[j];
    }
    s *= 0.125f;
    sc[kj] = s;
    mx = fmaxf(mx, s);
  }
  float sum = 0.f;
#pragma unroll
  for (int kj = 0; kj < 16; ++kj) { sc[kj] = expf(sc[kj] - mx); sum += sc[kj]; }
  const float inv = 1.f / sum;
  float ov[64] = {};
#pragma unroll
  for (int kj = 0; kj < 16; ++kj) {
    const float a = sc[kj] * inv;
    const f16* vr = &kv[win][kj][576 + h * 72];
#pragma unroll
    for (int c8 = 0; c8 < 8; ++c8) {
      f16x8 v8 = *(const f16x8*)(vr + c8 * 8);
#pragma unroll
      for (int j = 0; j < 8; ++j) ov[c8 * 8 + j] += a * (float)v8[j];
    }
  }
  f16* orow = O + (size_t)qtok * 512 + h * 64;
#pragma unroll
  for (int c8 = 0; c8 < 8; ++c8) {
    f16x8 t;
#pragma unroll
    for (int j = 0; j < 8; ++j) t[j] = (f16)ov[c8 * 8 + j];
    *(f16x8*)(orow + c8 * 8) = t;
  }
}

// ---------------------------------------------------------------------------
__global__ __launch_bounds__(256) void sn_sigma(const float* __restrict__ W,
                                                const float* __restrict__ u,
                                                float* __restrict__ inv_sigma)
{
  __shared__ float vsh[512];
  __shared__ float ush[256];
  __shared__ float red[256];
  const int t = (int)threadIdx.x;
  ush[t] = u[t];
  __syncthreads();
  float a0 = 0.f, a1 = 0.f;
  for (int j = 0; j < 256; ++j) {
    a0 += W[t * 256 + j] * ush[j];
    a1 += W[(t + 256) * 256 + j] * ush[j];
  }
  vsh[t] = a0; vsh[t + 256] = a1;
  red[t] = a0 * a0 + a1 * a1;
  __syncthreads();
  for (int s = 128; s > 0; s >>= 1) { if (t < s) red[t] += red[t + s]; __syncthreads(); }
  const float nv = sqrtf(red[0]) + 1e-12f;
  __syncthreads();
  const float invv = 1.f / nv;
  vsh[t] *= invv; vsh[t + 256] *= invv;
  __syncthreads();
  float u2 = 0.f;
  for (int i = 0; i < 512; ++i) u2 += vsh[i] * W[i * 256 + t];
  red[t] = u2 * u2;
  __syncthreads();
  for (int s = 128; s > 0; s >>= 1) { if (t < s) red[t] += red[t + s]; __syncthreads(); }
  const float nu = sqrtf(red[0]) + 1e-12f;
  __syncthreads();
  ush[t] = u2 / nu;
  __syncthreads();
  float d0 = 0.f, d1 = 0.f;
  for (int j = 0; j < 256; ++j) {
    d0 += W[t * 256 + j] * ush[j];
    d1 += W[(t + 256) * 256 + j] * ush[j];
  }
  red[t] = vsh[t] * d0 + vsh[t + 256] * d1;
  __syncthreads();
  for (int s = 128; s > 0; s >>= 1) { if (t < s) red[t] += red[t + s]; __syncthreads(); }
  if (t == 0) inv_sigma[0] = 1.f / red[0];
}

__global__ void fill_sentinel(float* __restrict__ out, long n, float val)
{
  const long i = (long)blockIdx.x * 256 + threadIdx.x;
  for (long k = i; k < n; k += (long)gridDim.x * 256) out[k] = val;
}

// ---------------------------------------------------------------------------
extern "C" void kernel_launch(void* const* d_in, const int* in_sizes, int n_in,
                              void* d_out, int out_size, void* d_ws, size_t ws_size,
                              hipStream_t stream)
{
  const int M = 196608;
  const int MC = 49152;
  constexpr size_t OFF_U   = 201326592ull;
  constexpr size_t OFF_OH  = 201326592ull + 150994944ull;
  constexpr size_t OFF_WT  = 402653184ull;
  constexpr size_t OFF_SIG = 415760384ull;
  constexpr size_t NEED    = OFF_SIG + 256ull;

  if (ws_size < NEED) {
    fill_sentinel<<<2048, 256, 0, stream>>>((float*)d_out, (long)out_size,
                                            (float)(ws_size >> 20));
    return;
  }

  char* ws = (char*)d_ws;
  f16* R     = (f16*)(ws);
  f16* U     = (f16*)(ws + OFF_U);
  f16* OH    = (f16*)(ws + OFF_OH);
  f16* WT    = (f16*)(ws + OFF_WT);
  float* sig = (float*)(ws + OFF_SIG);
  f16* X     = (f16*)d_out;

  const float* ff1_b = (const float*)d_in[2];
  const float* ff2_b = (const float*)d_in[28];

  f16* W_FF1 = WT;
  auto W_QKV = [&](int blk) { return WT + (blk ? 3276800 : 131072); };
  auto W_PW  = [&](int blk) { return WT + (blk ? 4063232 : 917504); };
  auto W_M1  = [&](int blk) { return WT + (blk ? 4325376 : 1179648); };
  auto W_M2  = [&](int blk) { return WT + (blk ? 5373952 : 2228224); };
  f16* W_FF2 = WT + 6422528;

  w_tr_tiled<<<32, 256, 0, stream>>>((const float*)d_in[1], W_FF1, 256, 512);
  for (int blk = 0; blk < 2; ++blk) {
    w_tr_tiled<<<192, 256, 0, stream>>>((const float*)d_in[blk ? 17 : 5], W_QKV(blk), 512, 1536);
    w_tr_tiled<<<64, 256, 0, stream>>>((const float*)d_in[blk ? 19 : 7], W_PW(blk), 512, 512);
    w_tr_tiled<<<256, 256, 0, stream>>>((const float*)d_in[blk ? 23 : 11], W_M1(blk), 512, 2048);
    w_tr_tiled<<<256, 256, 0, stream>>>((const float*)d_in[blk ? 25 : 13], W_M2(blk), 2048, 512);
  }
  w_tr_tiled<<<32, 256, 0, stream>>>((const float*)d_in[27], W_FF2, 512, 256);
  sn_sigma<<<1, 256, 0, stream>>>((const float*)d_in[27], (const float*)d_in[29], sig);

  // ---- ff1: R = gelu(x @ ff1_w + b)  (N=512, nct=2) ----
  cvt_f32_f16<<<24576, 256, 0, stream>>>((const float*)d_in[0], U, (long)M * 256 / 8);
  gemm<5><<<3072, 512, 0, stream>>>(U, W_FF1, ff1_b, nullptr, nullptr, R, nullptr,
                                    512, 256, 2);

  for (int blk = 0; blk < 2; ++blk) {
    const float* ln1g = (const float*)d_in[blk ? 15 : 3];
    const float* ln1b = (const float*)d_in[blk ? 16 : 4];
    const float* qkvb = (const float*)d_in[blk ? 18 : 6];
    const float* pb   = (const float*)d_in[blk ? 20 : 8];
    const float* ln2g = (const float*)d_in[blk ? 21 : 9];
    const float* ln2b = (const float*)d_in[blk ? 22 : 10];
    const float* m1b  = (const float*)d_in[blk ? 24 : 12];
    const float* m2b  = (const float*)d_in[blk ? 26 : 14];

    // attention: x += proj(attn(ln1(x)))
    ln_f16<<<4096, 256, 0, stream>>>(R, ln1g, ln1b, X, M);
    for (int mc = 0; mc < 4; ++mc) {
      const size_t ro = (size_t)mc * MC * 512;
      gemm<4><<<2304, 512, 0, stream>>>(X + ro, W_QKV(blk), qkvb, nullptr,
                                        nullptr, U, nullptr, 1536, 512, 6);
      if (blk == 0) win_attn<0><<<1536, 256, 0, stream>>>(U, OH);
      else          win_attn<8><<<1536, 256, 0, stream>>>(U, OH);
      gemm<6><<<768, 512, 0, stream>>>(OH, W_PW(blk), pb, R + ro,
                                       nullptr, R + ro, nullptr, 512, 512, 2);
    }
    // MLP: x += gelu(ln2(x) @ m1) @ m2
    ln_f16<<<4096, 256, 0, stream>>>(R, ln2g, ln2b, X, M);
    for (int mc = 0; mc < 4; ++mc) {
      const size_t ro = (size_t)mc * MC * 512;
      gemm<5><<<3072, 512, 0, stream>>>(X + ro, W_M1(blk), m1b, nullptr,
                                        nullptr, U, nullptr, 2048, 512, 8);
      gemm<6><<<768, 512, 0, stream>>>(U, W_M2(blk), m2b, R + ro,
                                       nullptr, R + ro, nullptr, 512, 2048, 2);
    }
  }

  // ---- spectral-norm linear -> d_out (fp32, N=256, nct=1) ----
  gemm<8><<<1536, 512, 0, stream>>>(R, W_FF2, ff2_b, nullptr, (float*)d_out,
                                    nullptr, sig, 256, 512, 1);
}

// Round 12
// 4784.077 us; speedup vs baseline: 1.0364x; 1.0152x over previous
//
#include <hip/hip_runtime.h>
#include <hip/hip_bf16.h>
#include <math.h>

typedef _Float16 f16;
typedef __attribute__((ext_vector_type(8))) _Float16 f16x8;
typedef __attribute__((ext_vector_type(4))) _Float16 f16x4;
typedef __attribute__((ext_vector_type(4))) float f32x4;

#define DINLINE __device__ __forceinline__

DINLINE float gelu_fast(float x) {
  // gelu ~= x * sigmoid(2t), t = 0.79788456*x*(1+0.044715x^2)
  float x2 = x * x;
  float z = x * __builtin_fmaf(-0.10294537f, x2, -2.30211422f);
  float E = __builtin_amdgcn_exp2f(z);
  return x * __builtin_amdgcn_rcpf(1.0f + E);
}
DINLINE void gload16(const void* g, void* l) {
  __builtin_amdgcn_global_load_lds((const __attribute__((address_space(1))) void*)g,
                                   (__attribute__((address_space(3))) void*)l, 16, 0, 0);
}

#define BAR       __builtin_amdgcn_s_barrier()
#define WAITVM(n) asm volatile("s_waitcnt vmcnt(" #n ")" ::: "memory")
#define CFE       asm volatile("" ::: "memory")

// ---------------------------------------------------------------------------
// GEMM 128x256 tile, BK=32, 512 thr / 8 waves (2M x 4N, wave-tile 64x64),
// 48KB dbuf LDS. r12 restructure: unroll-2 loop with COMPILE-TIME buffer
// offsets, 3 running global pointers (+32/tile), LDS reads via 2 base ints
// + ds_read offset immediates, NO explicit lgkmcnt (compiler emits
// fine-grained waits -> early MFMA overlaps later ds_reads). Counted
// vmcnt(3) prefetch, never drained mid-loop. Conflict-free XOR slot layout
// (verified r6-r11). Operand-swapped MFMA -> 4 consecutive C-cols/thread.
// C = A[M,K] @ Bt[N,K]^T. EPI: 1=gelu, 2=add f16 Cin, 4=store f16, 8=scale.
// Requires M%128==0, N%256==0, K%64==0 (NT even), K>=128.
// ---------------------------------------------------------------------------
template <int EPI>
__global__ __launch_bounds__(512, 4) void gemm(
    const f16* __restrict__ A, const f16* __restrict__ Bt,
    const float* __restrict__ bias, const f16* __restrict__ Cin,
    float* __restrict__ Cf, f16* __restrict__ Cb,
    const float* __restrict__ scale_ptr,
    int N, int K, int nct)
{
  __shared__ alignas(16) f16 smf[2 * 3 * 4096];  // [buf][A|B0|B1][128x32]

  // bijective XCD-chunked swizzle
  const int nwg = (int)gridDim.x;
  const int gid = (int)blockIdx.x;
  const int q = nwg >> 3, r = nwg & 7;
  const int xcd = gid & 7, idx = gid >> 3;
  const int swz = (xcd < r ? xcd * (q + 1) : r * (q + 1) + (xcd - r) * q) + idx;
  const int rt = swz / nct, ct = swz - rt * nct;
  const int m0 = rt << 7, n0 = ct << 8;          // 128 rows x 256 cols

  const int tid = (int)threadIdx.x;
  const int lane = tid & 63;
  const int wid = tid >> 6;
  const int wr = wid >> 2, wcn = wid & 3;        // wave -> 64x64 quadrant

  const int rsel = lane & 15, khi = lane >> 4;
  const int sx = (khi ^ ((rsel >> 1) & 3)) << 3;

  // staging: 3 gloads/thread/tile; row = tid>>2, inverse-swizzled slot
  const int srow = tid >> 2;
  const int sls = (tid & 3) ^ ((srow >> 1) & 3);
  const f16* pA  = A  + (size_t)(m0 + srow) * K + sls * 8;
  const f16* pB0 = Bt + (size_t)(n0 + srow) * K + sls * 8;
  const f16* pB1 = Bt + (size_t)(n0 + 128 + srow) * K + sls * 8;
  f16* ldst = smf + tid * 8;

  // LDS read bases (buf0); buf1 = +12288, frag i = +i*512 (fold to offsets)
  const int aB = (wr * 64 + rsel) * 32 + sx;
  const int bB = (1 + (wcn >> 1)) * 4096 + ((wcn & 1) * 64 + rsel) * 32 + sx;

  f32x4 acc[4][4] = {};
  const int NT = K >> 5;

#define STG(boff)                                                             \
  {                                                                           \
    gload16(pA,  ldst + (boff));                                              \
    gload16(pB0, ldst + (boff) + 4096);                                       \
    gload16(pB1, ldst + (boff) + 8192);                                       \
    pA += 32; pB0 += 32; pB1 += 32;                                           \
  }

#define CMP(boff)                                                             \
  {                                                                           \
    f16x8 aF[4], bF[4];                                                       \
    _Pragma("unroll")                                                         \
    for (int _i = 0; _i < 4; ++_i)                                            \
      aF[_i] = *(const f16x8*)(smf + (boff) + aB + _i * 512);                 \
    _Pragma("unroll")                                                         \
    for (int _i = 0; _i < 4; ++_i)                                            \
      bF[_i] = *(const f16x8*)(smf + (boff) + bB + _i * 512);                 \
    __builtin_amdgcn_s_setprio(1);                                            \
    _Pragma("unroll")                                                         \
    for (int _m = 0; _m < 4; ++_m)                                            \
      _Pragma("unroll")                                                       \
      for (int _n = 0; _n < 4; ++_n)                                          \
        acc[_m][_n] = __builtin_amdgcn_mfma_f32_16x16x32_f16(                 \
            bF[_n], aF[_m], acc[_m][_n], 0, 0, 0);                            \
    __builtin_amdgcn_s_setprio(0);                                            \
  }

  STG(0); STG(12288);                 // tiles 0,1 in flight (6 loads)
  for (int t = 0; t + 2 < NT; t += 2) {
    WAITVM(3); BAR; CFE;              // tile t (buf0) landed everywhere
    CMP(0);
    BAR; CFE;                         // all waves done reading buf0
    STG(0);                           // prefetch tile t+2
    WAITVM(3); BAR; CFE;              // tile t+1 (buf1) landed
    CMP(12288);
    BAR; CFE;
    STG(12288);                       // prefetch tile t+3
  }
  WAITVM(3); BAR; CFE;
  CMP(0);                             // tile NT-2
  BAR; CFE;
  WAITVM(0); BAR; CFE;
  CMP(12288);                         // tile NT-1

  // ---- vector epilogue: 4 consecutive cols per (m,n) frag ----
  const float scale = (EPI & 8) ? scale_ptr[0] : 1.0f;
  const int R0 = m0 + wr * 64, C0 = n0 + wcn * 64;
#pragma unroll
  for (int m = 0; m < 4; ++m) {
    const int row = R0 + m * 16 + rsel;
#pragma unroll
    for (int n = 0; n < 4; ++n) {
      const int col = C0 + n * 16 + (khi << 2);
      f32x4 v = acc[m][n];
      if (EPI & 8) {
#pragma unroll
        for (int j = 0; j < 4; ++j) v[j] *= scale;
      }
      f32x4 bb = *(const f32x4*)(bias + col);
#pragma unroll
      for (int j = 0; j < 4; ++j) v[j] += bb[j];
      if (EPI & 1) {
#pragma unroll
        for (int j = 0; j < 4; ++j) v[j] = gelu_fast(v[j]);
      }
      if (EPI & 2) {
        f16x4 c4 = *(const f16x4*)(Cin + (size_t)row * N + col);
#pragma unroll
        for (int j = 0; j < 4; ++j) v[j] += (float)c4[j];
      }
      if (EPI & 4) {
        f16x4 o;
#pragma unroll
        for (int j = 0; j < 4; ++j) o[j] = (f16)v[j];
        *(f16x4*)(Cb + (size_t)row * N + col) = o;
      } else {
        *(f32x4*)(Cf + (size_t)row * N + col) = v;
      }
    }
  }
#undef STG
#undef CMP
}

// ---------------------------------------------------------------------------
__global__ __launch_bounds__(256) void ln_f16(
    const f16* __restrict__ X, const float* __restrict__ g,
    const float* __restrict__ b, f16* __restrict__ Y, int ntok)
{
  const int lane = threadIdx.x & 63;
  const int c = lane * 8;
  const f32x4 g0 = *(const f32x4*)(g + c), g1 = *(const f32x4*)(g + c + 4);
  const f32x4 b0 = *(const f32x4*)(b + c), b1 = *(const f32x4*)(b + c + 4);
  for (int token = blockIdx.x * 4 + (threadIdx.x >> 6); token < ntok;
       token += gridDim.x * 4) {
    f16x8 v = *(const f16x8*)(X + (size_t)token * 512 + c);
    float vf[8];
    float s = 0.f, s2 = 0.f;
#pragma unroll
    for (int j = 0; j < 8; ++j) { vf[j] = (float)v[j]; s += vf[j]; s2 += vf[j] * vf[j]; }
#pragma unroll
    for (int o = 32; o > 0; o >>= 1) { s += __shfl_xor(s, o, 64); s2 += __shfl_xor(s2, o, 64); }
    const float mean = s * (1.f / 512.f);
    const float inv = rsqrtf(s2 * (1.f / 512.f) - mean * mean + 1e-5f);
    f16x8 o8;
#pragma unroll
    for (int j = 0; j < 4; ++j) {
      o8[j]     = (f16)((vf[j] - mean) * inv * g0[j] + b0[j]);
      o8[4 + j] = (f16)((vf[4 + j] - mean) * inv * g1[j] + b1[j]);
    }
    *(f16x8*)(Y + (size_t)token * 512 + c) = o8;
  }
}

__global__ __launch_bounds__(256) void cvt_f32_f16(const float* __restrict__ X,
                                                   f16* __restrict__ Y, long n8)
{
  const long i = (long)blockIdx.x * 256 + threadIdx.x;
  if (i >= n8) return;
  f32x4 v0 = *(const f32x4*)(X + i * 8), v1 = *(const f32x4*)(X + i * 8 + 4);
  f16x8 o8;
#pragma unroll
  for (int j = 0; j < 4; ++j) { o8[j] = (f16)v0[j]; o8[4 + j] = (f16)v1[j]; }
  *(f16x8*)(Y + i * 8) = o8;
}

__global__ __launch_bounds__(256) void w_tr_tiled(const float* __restrict__ W,
                                                  f16* __restrict__ Wt, int K, int N)
{
  __shared__ f16 td[64][66];
  const int nkt = K >> 6;
  const int kt = blockIdx.x % nkt, nt = blockIdx.x / nkt;
  const int k0 = kt << 6, n0 = nt << 6;
  const int col = threadIdx.x & 63, rq = threadIdx.x >> 6;
#pragma unroll
  for (int j = 0; j < 16; ++j) {
    const int row = j * 4 + rq;
    td[row][col] = (f16)W[(size_t)(k0 + row) * N + n0 + col];
  }
  __syncthreads();
#pragma unroll
  for (int j = 0; j < 16; ++j) {
    const int nrow = j * 4 + rq;
    Wt[(size_t)(n0 + nrow) * K + k0 + col] = td[col][nrow];
  }
}

// ---------------------------------------------------------------------------
template <int SHIFT>
__global__ __launch_bounds__(256) void win_attn(const f16* __restrict__ QKV,
                                                f16* __restrict__ O)
{
  __shared__ alignas(16) f16 kv[2][16][1160];
  const int wl0 = (int)blockIdx.x * 2;
  const int tid = (int)threadIdx.x;

  for (int i = tid; i < 4096; i += 256) {
    const int win = i >> 11;
    const int rem = i & 2047;
    const int row = rem >> 7;
    const int c8 = rem & 127;
    const int src = ((wl0 + win) * 16 + row + SHIFT) % 49152;
    const int sect = c8 >> 6;
    const int hh = (c8 >> 3) & 7;
    const int dd = (c8 & 7) * 8;
    *(f16x8*)(&kv[win][row][sect * 576 + hh * 72 + dd]) =
        *(const f16x8*)(QKV + (size_t)src * 1536 + 512 + c8 * 8);
  }

  const int win = tid >> 7, h = (tid >> 4) & 7, qi = tid & 15;
  const int qtok = ((wl0 + win) * 16 + qi + SHIFT) % 49152;
  f16x8 qv[8];
#pragma unroll
  for (int c8 = 0; c8 < 8; ++c8)
    qv[c8] = *(const f16x8*)(QKV + (size_t)qtok * 1536 + h * 64 + c8 * 8);

  __syncthreads();

  float sc[16];
  float mx = -1e30f;
#pragma unroll
  for (int kj = 0; kj < 16; ++kj) {
    const f16* kr = &kv[win][kj][h * 72];
    float s = 0.f;
#pragma unroll
    for (int c8 = 0; c8 < 8; ++c8) {
      f16x8 k8 = *(const f16x8*)(kr + c8 * 8);
#pragma unroll
      for (int j = 0; j < 8; ++j) s += (float)qv[c8][j] * (float)k8[j];
    }
    s *= 0.125f;
    sc[kj] = s;
    mx = fmaxf(mx, s);
  }
  float sum = 0.f;
#pragma unroll
  for (int kj = 0; kj < 16; ++kj) { sc[kj] = expf(sc[kj] - mx); sum += sc[kj]; }
  const float inv = 1.f / sum;
  float ov[64] = {};
#pragma unroll
  for (int kj = 0; kj < 16; ++kj) {
    const float a = sc[kj] * inv;
    const f16* vr = &kv[win][kj][576 + h * 72];
#pragma unroll
    for (int c8 = 0; c8 < 8; ++c8) {
      f16x8 v8 = *(const f16x8*)(vr + c8 * 8);
#pragma unroll
      for (int j = 0; j < 8; ++j) ov[c8 * 8 + j] += a * (float)v8[j];
    }
  }
  f16* orow = O + (size_t)qtok * 512 + h * 64;
#pragma unroll
  for (int c8 = 0; c8 < 8; ++c8) {
    f16x8 t;
#pragma unroll
    for (int j = 0; j < 8; ++j) t[j] = (f16)ov[c8 * 8 + j];
    *(f16x8*)(orow + c8 * 8) = t;
  }
}

// ---------------------------------------------------------------------------
__global__ __launch_bounds__(256) void sn_sigma(const float* __restrict__ W,
                                                const float* __restrict__ u,
                                                float* __restrict__ inv_sigma)
{
  __shared__ float vsh[512];
  __shared__ float ush[256];
  __shared__ float red[256];
  const int t = (int)threadIdx.x;
  ush[t] = u[t];
  __syncthreads();
  float a0 = 0.f, a1 = 0.f;
  for (int j = 0; j < 256; ++j) {
    a0 += W[t * 256 + j] * ush[j];
    a1 += W[(t + 256) * 256 + j] * ush[j];
  }
  vsh[t] = a0; vsh[t + 256] = a1;
  red[t] = a0 * a0 + a1 * a1;
  __syncthreads();
  for (int s = 128; s > 0; s >>= 1) { if (t < s) red[t] += red[t + s]; __syncthreads(); }
  const float nv = sqrtf(red[0]) + 1e-12f;
  __syncthreads();
  const float invv = 1.f / nv;
  vsh[t] *= invv; vsh[t + 256] *= invv;
  __syncthreads();
  float u2 = 0.f;
  for (int i = 0; i < 512; ++i) u2 += vsh[i] * W[i * 256 + t];
  red[t] = u2 * u2;
  __syncthreads();
  for (int s = 128; s > 0; s >>= 1) { if (t < s) red[t] += red[t + s]; __syncthreads(); }
  const float nu = sqrtf(red[0]) + 1e-12f;
  __syncthreads();
  ush[t] = u2 / nu;
  __syncthreads();
  float d0 = 0.f, d1 = 0.f;
  for (int j = 0; j < 256; ++j) {
    d0 += W[t * 256 + j] * ush[j];
    d1 += W[(t + 256) * 256 + j] * ush[j];
  }
  red[t] = vsh[t] * d0 + vsh[t + 256] * d1;
  __syncthreads();
  for (int s = 128; s > 0; s >>= 1) { if (t < s) red[t] += red[t + s]; __syncthreads(); }
  if (t == 0) inv_sigma[0] = 1.f / red[0];
}

__global__ void fill_sentinel(float* __restrict__ out, long n, float val)
{
  const long i = (long)blockIdx.x * 256 + threadIdx.x;
  for (long k = i; k < n; k += (long)gridDim.x * 256) out[k] = val;
}

// ---------------------------------------------------------------------------
extern "C" void kernel_launch(void* const* d_in, const int* in_sizes, int n_in,
                              void* d_out, int out_size, void* d_ws, size_t ws_size,
                              hipStream_t stream)
{
  const int M = 196608;
  const int MC = 49152;
  constexpr size_t OFF_U   = 201326592ull;
  constexpr size_t OFF_OH  = 201326592ull + 150994944ull;
  constexpr size_t OFF_WT  = 402653184ull;
  constexpr size_t OFF_SIG = 415760384ull;
  constexpr size_t NEED    = OFF_SIG + 256ull;

  if (ws_size < NEED) {
    fill_sentinel<<<2048, 256, 0, stream>>>((float*)d_out, (long)out_size,
                                            (float)(ws_size >> 20));
    return;
  }

  char* ws = (char*)d_ws;
  f16* R     = (f16*)(ws);
  f16* U     = (f16*)(ws + OFF_U);
  f16* OH    = (f16*)(ws + OFF_OH);
  f16* WT    = (f16*)(ws + OFF_WT);
  float* sig = (float*)(ws + OFF_SIG);
  f16* X     = (f16*)d_out;

  const float* ff1_b = (const float*)d_in[2];
  const float* ff2_b = (const float*)d_in[28];

  f16* W_FF1 = WT;
  auto W_QKV = [&](int blk) { return WT + (blk ? 3276800 : 131072); };
  auto W_PW  = [&](int blk) { return WT + (blk ? 4063232 : 917504); };
  auto W_M1  = [&](int blk) { return WT + (blk ? 4325376 : 1179648); };
  auto W_M2  = [&](int blk) { return WT + (blk ? 5373952 : 2228224); };
  f16* W_FF2 = WT + 6422528;

  w_tr_tiled<<<32, 256, 0, stream>>>((const float*)d_in[1], W_FF1, 256, 512);
  for (int blk = 0; blk < 2; ++blk) {
    w_tr_tiled<<<192, 256, 0, stream>>>((const float*)d_in[blk ? 17 : 5], W_QKV(blk), 512, 1536);
    w_tr_tiled<<<64, 256, 0, stream>>>((const float*)d_in[blk ? 19 : 7], W_PW(blk), 512, 512);
    w_tr_tiled<<<256, 256, 0, stream>>>((const float*)d_in[blk ? 23 : 11], W_M1(blk), 512, 2048);
    w_tr_tiled<<<256, 256, 0, stream>>>((const float*)d_in[blk ? 25 : 13], W_M2(blk), 2048, 512);
  }
  w_tr_tiled<<<32, 256, 0, stream>>>((const float*)d_in[27], W_FF2, 512, 256);
  sn_sigma<<<1, 256, 0, stream>>>((const float*)d_in[27], (const float*)d_in[29], sig);

  // ---- ff1: R = gelu(x @ ff1_w + b)  (N=512, nct=2) ----
  cvt_f32_f16<<<24576, 256, 0, stream>>>((const float*)d_in[0], U, (long)M * 256 / 8);
  gemm<5><<<3072, 512, 0, stream>>>(U, W_FF1, ff1_b, nullptr, nullptr, R, nullptr,
                                    512, 256, 2);

  for (int blk = 0; blk < 2; ++blk) {
    const float* ln1g = (const float*)d_in[blk ? 15 : 3];
    const float* ln1b = (const float*)d_in[blk ? 16 : 4];
    const float* qkvb = (const float*)d_in[blk ? 18 : 6];
    const float* pb   = (const float*)d_in[blk ? 20 : 8];
    const float* ln2g = (const float*)d_in[blk ? 21 : 9];
    const float* ln2b = (const float*)d_in[blk ? 22 : 10];
    const float* m1b  = (const float*)d_in[blk ? 24 : 12];
    const float* m2b  = (const float*)d_in[blk ? 26 : 14];

    // attention: x += proj(attn(ln1(x)))
    ln_f16<<<4096, 256, 0, stream>>>(R, ln1g, ln1b, X, M);
    for (int mc = 0; mc < 4; ++mc) {
      const size_t ro = (size_t)mc * MC * 512;
      gemm<4><<<2304, 512, 0, stream>>>(X + ro, W_QKV(blk), qkvb, nullptr,
                                        nullptr, U, nullptr, 1536, 512, 6);
      if (blk == 0) win_attn<0><<<1536, 256, 0, stream>>>(U, OH);
      else          win_attn<8><<<1536, 256, 0, stream>>>(U, OH);
      gemm<6><<<768, 512, 0, stream>>>(OH, W_PW(blk), pb, R + ro,
                                       nullptr, R + ro, nullptr, 512, 512, 2);
    }
    // MLP: x += gelu(ln2(x) @ m1) @ m2
    ln_f16<<<4096, 256, 0, stream>>>(R, ln2g, ln2b, X, M);
    for (int mc = 0; mc < 4; ++mc) {
      const size_t ro = (size_t)mc * MC * 512;
      gemm<5><<<3072, 512, 0, stream>>>(X + ro, W_M1(blk), m1b, nullptr,
                                        nullptr, U, nullptr, 2048, 512, 8);
      gemm<6><<<768, 512, 0, stream>>>(U, W_M2(blk), m2b, R + ro,
                                       nullptr, R + ro, nullptr, 512, 2048, 2);
    }
  }

  // ---- spectral-norm linear -> d_out (fp32, N=256, nct=1) ----
  gemm<8><<<1536, 512, 0, stream>>>(R, W_FF2, ff2_b, nullptr, (float*)d_out,
                                    nullptr, sig, 256, 512, 1);
}